// Round 19
// baseline (978.968 us; speedup 1.0000x reference)
//
#include <hip/hip_runtime.h>
#include <hip/hip_bf16.h>

// ---------------------------------------------------------------------------
// Swin window attention, MI355X gfx950 — split pipeline.
// prep (bf16 weights + pad-premasked frag bias) ->
//   xconv (roll+window gather, fp32->bf16, xw lives in d_out) ->
//   qkv GEMM v2: A-only LDS staging (32 KB -> 4 blocks/CU), B (w_qkv,
//     884 KB, L2/L1-hot: each panel re-read by 784 blocks) read DIRECT from
//     global as fragments; plain __syncthreads + next-tile prefetch (counted
//     vmcnt dropped: unsafe with compiler-issued B loads sharing the counter,
//     and 4 independent blocks/CU cover barrier drains via TLP) ->
//   attnproj (R18: 4 waves x 3 heads, swapped QK^T, IN-REGISTER PV via
//     6-shfl regroup, LDS = o_lds only -> 4 blocks/CU).
// ---------------------------------------------------------------------------

typedef __bf16 bf16x8 __attribute__((ext_vector_type(8)));
typedef float  floatx4 __attribute__((ext_vector_type(4)));
typedef short  short8  __attribute__((ext_vector_type(8)));
typedef unsigned long long u64;

#define MFMA16(a, b, c) __builtin_amdgcn_mfma_f32_16x16x32_bf16((a), (b), (c), 0, 0, 0)

static __device__ __forceinline__ void gload_lds16(const void* g, void* l) {
  __builtin_amdgcn_global_load_lds(
      (const __attribute__((address_space(1))) void*)g,
      (__attribute__((address_space(3))) void*)l, 16, 0, 0);
}

static __device__ __forceinline__ int src_off(int gm) {
  int win = gm / 49, t = gm - win * 49;
  int b = win >> 6, rr = win & 63;
  int wi = rr >> 3, wj = rr & 7;
  int ty = t / 7, tx = t - ty * 7;
  int y = wi * 7 + ty + 4; if (y >= 56) y -= 56;
  int x = wj * 7 + tx + 4; if (x >= 56) x -= 56;
  return ((b * 56 + y) * 56 + x) * 384;
}

static __device__ __forceinline__ int dst_off(int gm) {
  int win = gm / 49, t = gm - win * 49;
  int b = win >> 6, rr = win & 63;
  int wi = rr >> 3, wj = rr & 7;
  int ty = t / 7, tx = t - ty * 7;
  int y = wi * 7 + ty + 3; if (y >= 56) y -= 56;
  int x = wj * 7 + tx + 3; if (x >= 56) x -= 56;
  return ((b * 56 + y) * 56 + x) * 384;
}

static __device__ __forceinline__ float bf_lo(unsigned u) {
  union { unsigned v; float f; } c; c.v = u << 16; return c.f;
}
static __device__ __forceinline__ float bf_hi(unsigned u) {
  union { unsigned v; float f; } c; c.v = u & 0xFFFF0000u; return c.f;
}

// ---------------------------------------------------------------------------
// prep: bf16 weight copies + bias2 in the TRANSPOSED (S^T) fragment layout,
// PRE-MASKED with the pad mask (m>=49 || n>=49 -> -1e30).
__global__ __launch_bounds__(256) void prep_kernel(
    const float* __restrict__ w_qkv, const float* __restrict__ w_proj,
    const float* __restrict__ rel_table,
    __hip_bfloat16* __restrict__ wqkv_bf, __hip_bfloat16* __restrict__ wproj_bf,
    __hip_bfloat16* __restrict__ bias2) {
  const int N1 = 3 * 384 * 384;   // 442368
  const int N2 = 384 * 384;       // 147456
  const int N3 = 12 * 4 * 4 * 64 * 4;  // 196608
  int i = blockIdx.x * 256 + threadIdx.x;  // grid 3072*256 = N1+N2+N3
  if (i < N1) wqkv_bf[i] = __float2bfloat16(w_qkv[i]);
  int j = i - N1;
  if (j >= 0 && j < N2) wproj_bf[j] = __float2bfloat16(w_proj[j]);
  int k = i - N1 - N2;
  if (k >= 0 && k < N3) {
    int r = k & 3;
    int lp = (k >> 2) & 63;
    int ni = (k >> 8) & 3;
    int mi = (k >> 10) & 3;
    int head = k >> 12;
    int m = mi * 16 + (lp & 15);
    int n = ni * 16 + (lp >> 4) * 4 + r;
    float val = -1e30f;
    if (m < 49 && n < 49) {
      int dy = m / 7 - n / 7 + 6;
      int dx = m % 7 - n % 7 + 6;
      val = rel_table[(dy * 13 + dx) * 12 + head];
    }
    bias2[k] = __float2bfloat16(val);
  }
}

// ---------------------------------------------------------------------------
__global__ __launch_bounds__(256) void xconv_kernel(
    const float* __restrict__ x, __hip_bfloat16* __restrict__ xw) {
  int gid = blockIdx.x * 256 + threadIdx.x;   // 4,816,896 total
  int row = gid / 48;
  int c = (gid - row * 48) * 8;
  int so = src_off(row) + c;
  floatx4 a = *(const floatx4*)(x + so);
  floatx4 b = *(const floatx4*)(x + so + 4);
  union { __hip_bfloat16 h[8]; short8 s; } u;
#pragma unroll
  for (int i = 0; i < 4; ++i) {
    u.h[i]     = __float2bfloat16(a[i]);
    u.h[4 + i] = __float2bfloat16(b[i]);
  }
  *(short8*)(xw + (size_t)row * 384 + c) = u.s;
}

// ---------------------------------------------------------------------------
// QKV GEMM v2: 128x128 tile, BK=64; A-only LDS (2 x 16 KB dbuf = 32 KB ->
// 4 blocks/CU); B fragments direct from global (L2/L1-hot weight panels).
// Plain __syncthreads (vmcnt drain) + prefetch-next-before-compute; 4
// independent blocks/CU cover the barrier drains.
__global__ __launch_bounds__(256, 4) void qkv_kernel(
    const __hip_bfloat16* __restrict__ xw, const __hip_bfloat16* __restrict__ wq,
    const float* __restrict__ bqkv,
    __hip_bfloat16* __restrict__ qb, __hip_bfloat16* __restrict__ kb,
    __hip_bfloat16* __restrict__ vt) {
  __shared__ __hip_bfloat16 lds[2 * 8192];    // 32 KB: 2 x A-tile(128x64)
  int blk = blockIdx.x;                       // 7056 = 8 * 882
  int b2 = (blk & 7) * 882 + (blk >> 3);      // XCD-chunked swizzle (bijective)
  int mt = b2 / 9, nt = b2 - mt * 9;
  int tid = threadIdx.x;
  int l = tid & 63, wv = tid >> 6;
  int wm = wv >> 1, wn = wv & 1;
  int g = l >> 4, q16 = l & 15;

  const bool swapped = (nt >= 6);             // v-blocks: C^T fragment
  const int aro = (swapped ? wn : wm) * 64;   // A-frag (x) row base in tile
  const int bro = (swapped ? wm : wn) * 64;   // B-frag (W) row base in tile

  int sr = tid >> 3;                          // 0..31
  int sc = tid & 7;
  int scs = sc ^ (sr & 7);                    // (c*32+sr)&7 == sr&7

  const __hip_bfloat16* abase = xw + (size_t)(mt * 128) * 384;
  const __hip_bfloat16* bbase = wq + (size_t)(nt * 128) * 384;

  floatx4 acc[4][4];
#pragma unroll
  for (int i = 0; i < 4; ++i)
#pragma unroll
    for (int j = 0; j < 4; ++j)
#pragma unroll
      for (int r = 0; r < 4; ++r) acc[i][j][r] = 0.f;

  auto stage = [&](int buf, int kt) {         // A only: 4 x gload_lds16
    int k0 = kt * 64;
    __hip_bfloat16* la = lds + buf * 8192;
#pragma unroll
    for (int c = 0; c < 4; ++c) {
      int r = c * 32 + sr;
      gload_lds16(abase + (size_t)r * 384 + k0 + scs * 8, la + c * 2048 + tid * 8);
    }
  };

  auto compute = [&](int buf, int kt) {
    const __hip_bfloat16* la = lds + buf * 8192;
#pragma unroll
    for (int kk = 0; kk < 2; ++kk) {
      int kg = kt * 64 + kk * 32;
      bf16x8 af[4], bf[4];
#pragma unroll
      for (int i = 0; i < 4; ++i) {
        int r = aro + i * 16 + q16;
        int cp = (kk * 4 + g) ^ (r & 7);      // inverse swizzle on read
        af[i] = *(const bf16x8*)(la + r * 64 + cp * 8);
      }
#pragma unroll
      for (int i = 0; i < 4; ++i)             // B direct from L2-hot weights
        bf[i] = *(const bf16x8*)(bbase + (size_t)(bro + i * 16 + q16) * 384 + kg + g * 8);
      __builtin_amdgcn_s_setprio(1);
      if (!swapped) {
#pragma unroll
        for (int i = 0; i < 4; ++i)
#pragma unroll
          for (int j = 0; j < 4; ++j)
            acc[i][j] = MFMA16(af[i], bf[j], acc[i][j]);
      } else {
#pragma unroll
        for (int i = 0; i < 4; ++i)
#pragma unroll
          for (int j = 0; j < 4; ++j)
            acc[i][j] = MFMA16(bf[i], af[j], acc[i][j]);
      }
      __builtin_amdgcn_s_setprio(0);
    }
  };

  stage(0, 0);
  __syncthreads();                            // tile0 landed (vmcnt drain)
#pragma unroll
  for (int t = 0; t < 6; ++t) {
    if (t < 5) stage((t + 1) & 1, t + 1);     // prefetch overlaps compute(t)
    compute(t & 1, t);
    __syncthreads();                          // next tile landed / buf reusable
  }

  if (!swapped) {
    // q/k: C[gm][n]; lanes q16 -> consecutive nn (32B runs).
    const bool isq = (nt < 3);
    __hip_bfloat16* ob2 = isq ? qb : kb;
#pragma unroll
    for (int ni = 0; ni < 4; ++ni) {
      int n = nt * 128 + wn * 64 + ni * 16 + q16;
      float bn = bqkv[n];
      int nn = isq ? n : (n - 384);
#pragma unroll
      for (int mi = 0; mi < 4; ++mi) {
#pragma unroll
        for (int r = 0; r < 4; ++r) {
          int gm = mt * 128 + wm * 64 + mi * 16 + g * 4 + r;
          float v = acc[mi][ni][r] + bn;
          if (isq) v *= 0.17677669529663687f;  // 1/sqrt(32) folded into q
          ob2[gm * 384 + nn] = __float2bfloat16(v);
        }
      }
    }
  } else {
    // v: C^T[n][gm]; lanes q16 -> consecutive t (32B runs into vt rows).
    int win4[4], t4[4];
#pragma unroll
    for (int bj = 0; bj < 4; ++bj) {
      int gm = mt * 128 + wn * 64 + bj * 16 + q16;
      int w = gm / 49;
      win4[bj] = w;
      t4[bj] = gm - w * 49;
    }
#pragma unroll
    for (int ai = 0; ai < 4; ++ai) {
#pragma unroll
      for (int r = 0; r < 4; ++r) {
        int n = nt * 128 + wm * 64 + ai * 16 + g * 4 + r;
        float bn = bqkv[n];
        int nnv = n - 768;                    // head*32 + d
#pragma unroll
        for (int bj = 0; bj < 4; ++bj) {
          vt[((size_t)win4[bj] * 384 + nnv) * 64 + t4[bj]] =
              __float2bfloat16(acc[ai][bj][r] + bn);
        }
      }
    }
  }
}

// ---------------------------------------------------------------------------
// attnproj (R18): 256 threads, 4 waves x 3 heads; swapped QK^T; in-register
// PV via 6-shfl regroup. LDS = o_lds only (38,416 B) -> 4 blocks/CU.
__global__ __launch_bounds__(256, 4) void attnproj_kernel(
    const __hip_bfloat16* __restrict__ qb, const __hip_bfloat16* __restrict__ kb,
    const __hip_bfloat16* __restrict__ vt, const __hip_bfloat16* __restrict__ bias2,
    const __hip_bfloat16* __restrict__ wp, const float* __restrict__ bproj,
    float* __restrict__ out) {
  __shared__ __hip_bfloat16 o_lds[49][392];    // 38,416 B (the only LDS)
  int blk = blockIdx.x;                        // 2048 = 8 * 256
  int win = (blk & 7) * 256 + (blk >> 3);      // XCD-chunked swizzle
  int tid = threadIdx.x;
  int wv = tid >> 6, l = tid & 63;
  int g = l >> 4, q16 = l & 15;
  int wr = win & 63;
  const bool lastrow = ((wr >> 3) == 7);
  const bool lastcol = ((wr & 7) == 7);

  // shift-mask badbits only for boundary windows (pad mask is in bias2).
  unsigned long long badbits = 0ull;
  if (lastrow || lastcol) {
#pragma unroll
    for (int mi = 0; mi < 4; ++mi) {
      int m = mi * 16 + q16;
      int m7 = m % 7;
      bool m28 = (m >= 28), m74 = (m7 >= 4);
#pragma unroll
      for (int ni = 0; ni < 4; ++ni) {
#pragma unroll
        for (int r = 0; r < 4; ++r) {
          int n = ni * 16 + g * 4 + r;
          bool bad = (lastrow && (m28 != (n >= 28))) ||
                     (lastcol && (m74 != ((n % 7) >= 4)));
          if (bad) badbits |= (1ull << (mi * 16 + ni * 4 + r));
        }
      }
    }
  }

  floatx4 zc;
  zc[0] = zc[1] = zc[2] = zc[3] = 0.f;

#pragma unroll 1
  for (int hh = 0; hh < 3; ++hh) {
    int head = wv * 3 + hh;
    const __hip_bfloat16* qp = qb + (size_t)(win * 49) * 384 + head * 32 + g * 8;
    const __hip_bfloat16* kp = kb + (size_t)(win * 49) * 384 + head * 32 + g * 8;

    bf16x8 bk[4];
#pragma unroll
    for (int ni = 0; ni < 4; ++ni) {
      int row = ni * 16 + q16;
      row = row < 49 ? row : 48;               // pad rows masked via bias
      bk[ni] = *(const bf16x8*)(kp + row * 384);
    }
    // V^T A-frags: A[d][k=t], row d = ai*16+q16, k = ks*32+g*8 (vt: [d][t=64])
    const __hip_bfloat16* vp = vt + ((size_t)win * 384 + head * 32) * 64;
    bf16x8 va[2][2];
#pragma unroll
    for (int ai = 0; ai < 2; ++ai)
#pragma unroll
      for (int ks = 0; ks < 2; ++ks)
        va[ai][ks] = *(const bf16x8*)(vp + (ai * 16 + q16) * 64 + ks * 32 + g * 8);

    const __hip_bfloat16* b2 = bias2 + (size_t)head * 4096;

#pragma unroll
    for (int mi = 0; mi < 4; ++mi) {
      int arow = mi * 16 + q16;
      arow = arow < 49 ? arow : 48;
      bf16x8 aqm = *(const bf16x8*)(qp + arow * 384);

      floatx4 stm[4];                          // S^T[ni][this mi]
      __builtin_amdgcn_s_setprio(1);
#pragma unroll
      for (int ni = 0; ni < 4; ++ni)
        stm[ni] = MFMA16(bk[ni], aqm, zc);
      __builtin_amdgcn_s_setprio(0);

      uint2 braw[4];
#pragma unroll
      for (int ni = 0; ni < 4; ++ni)
        braw[ni] = *(const uint2*)(b2 + ((mi * 4 + ni) * 64 + l) * 4);

      float vals[4][4];
      float mx = -1e30f;
#pragma unroll
      for (int ni = 0; ni < 4; ++ni) {
#pragma unroll
        for (int r = 0; r < 4; ++r) {
          float bb = (r == 0) ? bf_lo(braw[ni].x) : (r == 1) ? bf_hi(braw[ni].x)
                     : (r == 2) ? bf_lo(braw[ni].y) : bf_hi(braw[ni].y);
          float v = stm[ni][r] + bb;           // pad entries: bb = -1e30
          if ((badbits >> (mi * 16 + ni * 4 + r)) & 1) v = -1e30f;
          vals[ni][r] = v;
          mx = fmaxf(mx, v);
        }
      }
      mx = fmaxf(mx, __shfl_xor(mx, 16));
      mx = fmaxf(mx, __shfl_xor(mx, 32));
      float sum = 0.f;
#pragma unroll
      for (int ni = 0; ni < 4; ++ni) {
#pragma unroll
        for (int r = 0; r < 4; ++r) {
          float p = __expf(vals[ni][r] - mx);  // masked -> exact 0
          vals[ni][r] = p;
          sum += p;
        }
      }
      sum += __shfl_xor(sum, 16);
      sum += __shfl_xor(sum, 32);
      float inv = 1.0f / sum;

      // pack normalized P^T: pk4[ni] = 4 bf16 {t = ni*16 + g*4 + r}
      u64 pk4[4];
#pragma unroll
      for (int ni = 0; ni < 4; ++ni) {
        union { __hip_bfloat16 h[4]; u64 u; } pk;
#pragma unroll
        for (int r = 0; r < 4; ++r) pk.h[r] = __float2bfloat16(vals[ni][r] * inv);
        pk4[ni] = pk.u;
      }

      // regroup to PV B-frags (row m=q16, k=t): verified 6-shfl network (R17)
      bf16x8 bp[2];
#pragma unroll
      for (int ks = 0; ks < 2; ++ks) {
        u64 A  = pk4[2 * ks];
        u64 A3 = pk4[2 * ks + 1];
        u64 B16 = __shfl_xor(A, 16);
        u64 B32 = __shfl_xor(A, 32);
        u64 B48 = __shfl_xor(A, 48);
        u64 C16 = __shfl_xor(A3, 16);
        u64 C32 = __shfl_xor(A3, 32);
        u64 C48 = __shfl_xor(A3, 48);
        u64 lo = (g == 0) ? A : (g == 1) ? B48 : (g == 2) ? C32 : C16;
        u64 hi = (g == 0) ? B16 : (g == 1) ? B32 : (g == 2) ? C48 : A3;
        union { u64 w[2]; bf16x8 v; } cb;
        cb.w[0] = lo; cb.w[1] = hi;
        bp[ks] = cb.v;
      }

      // PV: O^T[d][m] = sum_t V^T[d][t] P[m][t]; C row d = ai*16+g*4+r, col m=q16
      floatx4 o2[2];
      o2[0] = o2[1] = zc;
      __builtin_amdgcn_s_setprio(1);
#pragma unroll
      for (int ai = 0; ai < 2; ++ai)
#pragma unroll
        for (int ks = 0; ks < 2; ++ks)
          o2[ai] = MFMA16(va[ai][ks], bp[ks], o2[ai]);
      __builtin_amdgcn_s_setprio(0);

      int m = mi * 16 + q16;
      if (m < 49) {
#pragma unroll
        for (int ai = 0; ai < 2; ++ai)
#pragma unroll
          for (int r = 0; r < 4; ++r)
            o_lds[m][head * 32 + ai * 16 + g * 4 + r] = __float2bfloat16(o2[ai][r]);
      }
    }
  }

  __syncthreads();                             // all heads' O in o_lds

  // ---- proj: wave wv -> cols [wv*96, wv*96+96), 2 passes of 48 ----
#pragma unroll 1
  for (int pass = 0; pass < 2; ++pass) {
    int n0 = wv * 96 + pass * 48;
    floatx4 pacc[4][3];
#pragma unroll
    for (int i = 0; i < 4; ++i)
#pragma unroll
      for (int j = 0; j < 3; ++j) pacc[i][j] = zc;

#pragma unroll
    for (int kk = 0; kk < 12; ++kk) {
      int k0 = kk * 32;
      bf16x8 af[4], bfr[3];
#pragma unroll
      for (int mi = 0; mi < 4; ++mi) {
        int row = mi * 16 + q16;
        row = row < 49 ? row : 48;
        af[mi] = *(const bf16x8*)&o_lds[row][k0 + g * 8];
      }
#pragma unroll
      for (int ni = 0; ni < 3; ++ni)
        bfr[ni] = *(const bf16x8*)(wp + (size_t)(n0 + ni * 16 + q16) * 384 + k0 + g * 8);
      __builtin_amdgcn_s_setprio(1);
#pragma unroll
      for (int mi = 0; mi < 4; ++mi)
#pragma unroll
        for (int ni = 0; ni < 3; ++ni)
          pacc[mi][ni] = MFMA16(af[mi], bfr[ni], pacc[mi][ni]);
      __builtin_amdgcn_s_setprio(0);
    }

#pragma unroll
    for (int mi = 0; mi < 4; ++mi) {
#pragma unroll
      for (int r = 0; r < 4; ++r) {
        int m = mi * 16 + g * 4 + r;
        if (m < 49) {
          int off = dst_off(win * 49 + m);
#pragma unroll
          for (int ni = 0; ni < 3; ++ni) {
            int n = n0 + ni * 16 + q16;
            out[off + n] = pacc[mi][ni][r] + bproj[n];
          }
        }
      }
    }
  }
}

// ---------------------------------------------------------------------------
extern "C" void kernel_launch(void* const* d_in, const int* in_sizes, int n_in,
                              void* d_out, int out_size, void* d_ws, size_t ws_size,
                              hipStream_t stream) {
  const float* x         = (const float*)d_in[0];
  const float* w_qkv     = (const float*)d_in[1];
  const float* b_qkv     = (const float*)d_in[2];
  const float* w_proj    = (const float*)d_in[3];
  const float* b_proj    = (const float*)d_in[4];
  const float* rel_table = (const float*)d_in[5];
  float* out = (float*)d_out;

  char* ws = (char*)d_ws;
  // Workspace layout (total 256,376,832 B):
  const size_t OFF_WQKV  = 0;                        //   884,736
  const size_t OFF_WPROJ = 884736;                   //   294,912
  const size_t OFF_BIAS2 = 1179648;                  //   393,216
  const size_t OFF_Q     = 1572864;                  //  77,070,336
  const size_t OFF_K     = OFF_Q + 77070336;         //  77,070,336
  const size_t OFF_VT    = OFF_K + 77070336;         // 100,663,296 (v^T, 64-pad)

  __hip_bfloat16* wqkv_bf  = (__hip_bfloat16*)(ws + OFF_WQKV);
  __hip_bfloat16* wproj_bf = (__hip_bfloat16*)(ws + OFF_WPROJ);
  __hip_bfloat16* bias2    = (__hip_bfloat16*)(ws + OFF_BIAS2);
  __hip_bfloat16* qb       = (__hip_bfloat16*)(ws + OFF_Q);
  __hip_bfloat16* kb       = (__hip_bfloat16*)(ws + OFF_K);
  __hip_bfloat16* vt       = (__hip_bfloat16*)(ws + OFF_VT);
  // xw lives in d_out: dead scratch until attnproj fully overwrites out.
  __hip_bfloat16* xw       = (__hip_bfloat16*)d_out;

  // No vt memset: pad cols t=49..63 only ever multiply exactly-zero P, and
  // stale/0xAA bf16 patterns are finite, so 0*pad == 0.

  prep_kernel<<<3072, 256, 0, stream>>>(w_qkv, w_proj, rel_table, wqkv_bf, wproj_bf, bias2);
  xconv_kernel<<<18816, 256, 0, stream>>>(x, xw);
  qkv_kernel<<<7056, 256, 0, stream>>>(xw, wqkv_bf, b_qkv, qb, kb, vt);
  attnproj_kernel<<<2048, 256, 0, stream>>>(qb, kb, vt, bias2, wproj_bf, b_proj, out);
}

// Round 20
// 496.726 us; speedup vs baseline: 1.9708x; 1.9708x over previous
//
#include <hip/hip_runtime.h>
#include <hip/hip_bf16.h>

// ---------------------------------------------------------------------------
// Swin window attention, MI355X gfx950 — split pipeline.
// prep (bf16 weights + pad-premasked frag bias) ->
//   xconv (roll+window gather, fp32->bf16, xw lives in d_out) ->
//   qkv GEMM v2: A-only LDS staging (32 KB), B (w_qkv, L2-hot) direct from
//     global; __launch_bounds__(256,3): R19's (256,4)=128-reg cap spilled
//     (WRITE 2.1 GB, 762 us) — 170-reg budget fits the ~150-reg demand,
//     3 blocks/CU = 12 waves (vs 8 for the old A+B-staged 64 KB version) ->
//   attnproj (R18: 4 waves x 3 heads, swapped QK^T, IN-REGISTER PV via
//     6-shfl regroup, LDS = o_lds only -> 4 blocks/CU).
// ---------------------------------------------------------------------------

typedef __bf16 bf16x8 __attribute__((ext_vector_type(8)));
typedef float  floatx4 __attribute__((ext_vector_type(4)));
typedef short  short8  __attribute__((ext_vector_type(8)));
typedef unsigned long long u64;

#define MFMA16(a, b, c) __builtin_amdgcn_mfma_f32_16x16x32_bf16((a), (b), (c), 0, 0, 0)

static __device__ __forceinline__ void gload_lds16(const void* g, void* l) {
  __builtin_amdgcn_global_load_lds(
      (const __attribute__((address_space(1))) void*)g,
      (__attribute__((address_space(3))) void*)l, 16, 0, 0);
}

static __device__ __forceinline__ int src_off(int gm) {
  int win = gm / 49, t = gm - win * 49;
  int b = win >> 6, rr = win & 63;
  int wi = rr >> 3, wj = rr & 7;
  int ty = t / 7, tx = t - ty * 7;
  int y = wi * 7 + ty + 4; if (y >= 56) y -= 56;
  int x = wj * 7 + tx + 4; if (x >= 56) x -= 56;
  return ((b * 56 + y) * 56 + x) * 384;
}

static __device__ __forceinline__ int dst_off(int gm) {
  int win = gm / 49, t = gm - win * 49;
  int b = win >> 6, rr = win & 63;
  int wi = rr >> 3, wj = rr & 7;
  int ty = t / 7, tx = t - ty * 7;
  int y = wi * 7 + ty + 3; if (y >= 56) y -= 56;
  int x = wj * 7 + tx + 3; if (x >= 56) x -= 56;
  return ((b * 56 + y) * 56 + x) * 384;
}

static __device__ __forceinline__ float bf_lo(unsigned u) {
  union { unsigned v; float f; } c; c.v = u << 16; return c.f;
}
static __device__ __forceinline__ float bf_hi(unsigned u) {
  union { unsigned v; float f; } c; c.v = u & 0xFFFF0000u; return c.f;
}

// ---------------------------------------------------------------------------
// prep: bf16 weight copies + bias2 in the TRANSPOSED (S^T) fragment layout,
// PRE-MASKED with the pad mask (m>=49 || n>=49 -> -1e30).
__global__ __launch_bounds__(256) void prep_kernel(
    const float* __restrict__ w_qkv, const float* __restrict__ w_proj,
    const float* __restrict__ rel_table,
    __hip_bfloat16* __restrict__ wqkv_bf, __hip_bfloat16* __restrict__ wproj_bf,
    __hip_bfloat16* __restrict__ bias2) {
  const int N1 = 3 * 384 * 384;   // 442368
  const int N2 = 384 * 384;       // 147456
  const int N3 = 12 * 4 * 4 * 64 * 4;  // 196608
  int i = blockIdx.x * 256 + threadIdx.x;  // grid 3072*256 = N1+N2+N3
  if (i < N1) wqkv_bf[i] = __float2bfloat16(w_qkv[i]);
  int j = i - N1;
  if (j >= 0 && j < N2) wproj_bf[j] = __float2bfloat16(w_proj[j]);
  int k = i - N1 - N2;
  if (k >= 0 && k < N3) {
    int r = k & 3;
    int lp = (k >> 2) & 63;
    int ni = (k >> 8) & 3;
    int mi = (k >> 10) & 3;
    int head = k >> 12;
    int m = mi * 16 + (lp & 15);
    int n = ni * 16 + (lp >> 4) * 4 + r;
    float val = -1e30f;
    if (m < 49 && n < 49) {
      int dy = m / 7 - n / 7 + 6;
      int dx = m % 7 - n % 7 + 6;
      val = rel_table[(dy * 13 + dx) * 12 + head];
    }
    bias2[k] = __float2bfloat16(val);
  }
}

// ---------------------------------------------------------------------------
__global__ __launch_bounds__(256) void xconv_kernel(
    const float* __restrict__ x, __hip_bfloat16* __restrict__ xw) {
  int gid = blockIdx.x * 256 + threadIdx.x;   // 4,816,896 total
  int row = gid / 48;
  int c = (gid - row * 48) * 8;
  int so = src_off(row) + c;
  floatx4 a = *(const floatx4*)(x + so);
  floatx4 b = *(const floatx4*)(x + so + 4);
  union { __hip_bfloat16 h[8]; short8 s; } u;
#pragma unroll
  for (int i = 0; i < 4; ++i) {
    u.h[i]     = __float2bfloat16(a[i]);
    u.h[4 + i] = __float2bfloat16(b[i]);
  }
  *(short8*)(xw + (size_t)row * 384 + c) = u.s;
}

// ---------------------------------------------------------------------------
// QKV GEMM v2: 128x128 tile, BK=64; A-only LDS (2 x 16 KB dbuf = 32 KB);
// B fragments direct from global (L2/L1-hot weight panels). Plain
// __syncthreads + prefetch-next-before-compute. (256,3): no spill.
__global__ __launch_bounds__(256, 3) void qkv_kernel(
    const __hip_bfloat16* __restrict__ xw, const __hip_bfloat16* __restrict__ wq,
    const float* __restrict__ bqkv,
    __hip_bfloat16* __restrict__ qb, __hip_bfloat16* __restrict__ kb,
    __hip_bfloat16* __restrict__ vt) {
  __shared__ __hip_bfloat16 lds[2 * 8192];    // 32 KB: 2 x A-tile(128x64)
  int blk = blockIdx.x;                       // 7056 = 8 * 882
  int b2 = (blk & 7) * 882 + (blk >> 3);      // XCD-chunked swizzle (bijective)
  int mt = b2 / 9, nt = b2 - mt * 9;
  int tid = threadIdx.x;
  int l = tid & 63, wv = tid >> 6;
  int wm = wv >> 1, wn = wv & 1;
  int g = l >> 4, q16 = l & 15;

  const bool swapped = (nt >= 6);             // v-blocks: C^T fragment
  const int aro = (swapped ? wn : wm) * 64;   // A-frag (x) row base in tile
  const int bro = (swapped ? wm : wn) * 64;   // B-frag (W) row base in tile

  int sr = tid >> 3;                          // 0..31
  int sc = tid & 7;
  int scs = sc ^ (sr & 7);                    // (c*32+sr)&7 == sr&7

  const __hip_bfloat16* abase = xw + (size_t)(mt * 128) * 384;
  const __hip_bfloat16* bbase = wq + (size_t)(nt * 128) * 384;

  floatx4 acc[4][4];
#pragma unroll
  for (int i = 0; i < 4; ++i)
#pragma unroll
    for (int j = 0; j < 4; ++j)
#pragma unroll
      for (int r = 0; r < 4; ++r) acc[i][j][r] = 0.f;

  auto stage = [&](int buf, int kt) {         // A only: 4 x gload_lds16
    int k0 = kt * 64;
    __hip_bfloat16* la = lds + buf * 8192;
#pragma unroll
    for (int c = 0; c < 4; ++c) {
      int r = c * 32 + sr;
      gload_lds16(abase + (size_t)r * 384 + k0 + scs * 8, la + c * 2048 + tid * 8);
    }
  };

  auto compute = [&](int buf, int kt) {
    const __hip_bfloat16* la = lds + buf * 8192;
#pragma unroll
    for (int kk = 0; kk < 2; ++kk) {
      int kg = kt * 64 + kk * 32;
      bf16x8 af[4], bf[4];
#pragma unroll
      for (int i = 0; i < 4; ++i) {
        int r = aro + i * 16 + q16;
        int cp = (kk * 4 + g) ^ (r & 7);      // inverse swizzle on read
        af[i] = *(const bf16x8*)(la + r * 64 + cp * 8);
      }
#pragma unroll
      for (int i = 0; i < 4; ++i)             // B direct from L2-hot weights
        bf[i] = *(const bf16x8*)(bbase + (size_t)(bro + i * 16 + q16) * 384 + kg + g * 8);
      __builtin_amdgcn_s_setprio(1);
      if (!swapped) {
#pragma unroll
        for (int i = 0; i < 4; ++i)
#pragma unroll
          for (int j = 0; j < 4; ++j)
            acc[i][j] = MFMA16(af[i], bf[j], acc[i][j]);
      } else {
#pragma unroll
        for (int i = 0; i < 4; ++i)
#pragma unroll
          for (int j = 0; j < 4; ++j)
            acc[i][j] = MFMA16(bf[i], af[j], acc[i][j]);
      }
      __builtin_amdgcn_s_setprio(0);
    }
  };

  stage(0, 0);
  __syncthreads();                            // tile0 landed (vmcnt drain)
#pragma unroll
  for (int t = 0; t < 6; ++t) {
    if (t < 5) stage((t + 1) & 1, t + 1);     // prefetch overlaps compute(t)
    compute(t & 1, t);
    __syncthreads();                          // next tile landed / buf reusable
  }

  if (!swapped) {
    // q/k: C[gm][n]; lanes q16 -> consecutive nn (32B runs).
    const bool isq = (nt < 3);
    __hip_bfloat16* ob2 = isq ? qb : kb;
#pragma unroll
    for (int ni = 0; ni < 4; ++ni) {
      int n = nt * 128 + wn * 64 + ni * 16 + q16;
      float bn = bqkv[n];
      int nn = isq ? n : (n - 384);
#pragma unroll
      for (int mi = 0; mi < 4; ++mi) {
#pragma unroll
        for (int r = 0; r < 4; ++r) {
          int gm = mt * 128 + wm * 64 + mi * 16 + g * 4 + r;
          float v = acc[mi][ni][r] + bn;
          if (isq) v *= 0.17677669529663687f;  // 1/sqrt(32) folded into q
          ob2[gm * 384 + nn] = __float2bfloat16(v);
        }
      }
    }
  } else {
    // v: C^T[n][gm]; lanes q16 -> consecutive t (32B runs into vt rows).
    int win4[4], t4[4];
#pragma unroll
    for (int bj = 0; bj < 4; ++bj) {
      int gm = mt * 128 + wn * 64 + bj * 16 + q16;
      int w = gm / 49;
      win4[bj] = w;
      t4[bj] = gm - w * 49;
    }
#pragma unroll
    for (int ai = 0; ai < 4; ++ai) {
#pragma unroll
      for (int r = 0; r < 4; ++r) {
        int n = nt * 128 + wm * 64 + ai * 16 + g * 4 + r;
        float bn = bqkv[n];
        int nnv = n - 768;                    // head*32 + d
#pragma unroll
        for (int bj = 0; bj < 4; ++bj) {
          vt[((size_t)win4[bj] * 384 + nnv) * 64 + t4[bj]] =
              __float2bfloat16(acc[ai][bj][r] + bn);
        }
      }
    }
  }
}

// ---------------------------------------------------------------------------
// attnproj (R18): 256 threads, 4 waves x 3 heads; swapped QK^T; in-register
// PV via 6-shfl regroup. LDS = o_lds only (38,416 B) -> 4 blocks/CU.
__global__ __launch_bounds__(256, 4) void attnproj_kernel(
    const __hip_bfloat16* __restrict__ qb, const __hip_bfloat16* __restrict__ kb,
    const __hip_bfloat16* __restrict__ vt, const __hip_bfloat16* __restrict__ bias2,
    const __hip_bfloat16* __restrict__ wp, const float* __restrict__ bproj,
    float* __restrict__ out) {
  __shared__ __hip_bfloat16 o_lds[49][392];    // 38,416 B (the only LDS)
  int blk = blockIdx.x;                        // 2048 = 8 * 256
  int win = (blk & 7) * 256 + (blk >> 3);      // XCD-chunked swizzle
  int tid = threadIdx.x;
  int wv = tid >> 6, l = tid & 63;
  int g = l >> 4, q16 = l & 15;
  int wr = win & 63;
  const bool lastrow = ((wr >> 3) == 7);
  const bool lastcol = ((wr & 7) == 7);

  // shift-mask badbits only for boundary windows (pad mask is in bias2).
  unsigned long long badbits = 0ull;
  if (lastrow || lastcol) {
#pragma unroll
    for (int mi = 0; mi < 4; ++mi) {
      int m = mi * 16 + q16;
      int m7 = m % 7;
      bool m28 = (m >= 28), m74 = (m7 >= 4);
#pragma unroll
      for (int ni = 0; ni < 4; ++ni) {
#pragma unroll
        for (int r = 0; r < 4; ++r) {
          int n = ni * 16 + g * 4 + r;
          bool bad = (lastrow && (m28 != (n >= 28))) ||
                     (lastcol && (m74 != ((n % 7) >= 4)));
          if (bad) badbits |= (1ull << (mi * 16 + ni * 4 + r));
        }
      }
    }
  }

  floatx4 zc;
  zc[0] = zc[1] = zc[2] = zc[3] = 0.f;

#pragma unroll 1
  for (int hh = 0; hh < 3; ++hh) {
    int head = wv * 3 + hh;
    const __hip_bfloat16* qp = qb + (size_t)(win * 49) * 384 + head * 32 + g * 8;
    const __hip_bfloat16* kp = kb + (size_t)(win * 49) * 384 + head * 32 + g * 8;

    bf16x8 bk[4];
#pragma unroll
    for (int ni = 0; ni < 4; ++ni) {
      int row = ni * 16 + q16;
      row = row < 49 ? row : 48;               // pad rows masked via bias
      bk[ni] = *(const bf16x8*)(kp + row * 384);
    }
    // V^T A-frags: A[d][k=t], row d = ai*16+q16, k = ks*32+g*8 (vt: [d][t=64])
    const __hip_bfloat16* vp = vt + ((size_t)win * 384 + head * 32) * 64;
    bf16x8 va[2][2];
#pragma unroll
    for (int ai = 0; ai < 2; ++ai)
#pragma unroll
      for (int ks = 0; ks < 2; ++ks)
        va[ai][ks] = *(const bf16x8*)(vp + (ai * 16 + q16) * 64 + ks * 32 + g * 8);

    const __hip_bfloat16* b2 = bias2 + (size_t)head * 4096;

#pragma unroll
    for (int mi = 0; mi < 4; ++mi) {
      int arow = mi * 16 + q16;
      arow = arow < 49 ? arow : 48;
      bf16x8 aqm = *(const bf16x8*)(qp + arow * 384);

      floatx4 stm[4];                          // S^T[ni][this mi]
      __builtin_amdgcn_s_setprio(1);
#pragma unroll
      for (int ni = 0; ni < 4; ++ni)
        stm[ni] = MFMA16(bk[ni], aqm, zc);
      __builtin_amdgcn_s_setprio(0);

      uint2 braw[4];
#pragma unroll
      for (int ni = 0; ni < 4; ++ni)
        braw[ni] = *(const uint2*)(b2 + ((mi * 4 + ni) * 64 + l) * 4);

      float vals[4][4];
      float mx = -1e30f;
#pragma unroll
      for (int ni = 0; ni < 4; ++ni) {
#pragma unroll
        for (int r = 0; r < 4; ++r) {
          float bb = (r == 0) ? bf_lo(braw[ni].x) : (r == 1) ? bf_hi(braw[ni].x)
                     : (r == 2) ? bf_lo(braw[ni].y) : bf_hi(braw[ni].y);
          float v = stm[ni][r] + bb;           // pad entries: bb = -1e30
          if ((badbits >> (mi * 16 + ni * 4 + r)) & 1) v = -1e30f;
          vals[ni][r] = v;
          mx = fmaxf(mx, v);
        }
      }
      mx = fmaxf(mx, __shfl_xor(mx, 16));
      mx = fmaxf(mx, __shfl_xor(mx, 32));
      float sum = 0.f;
#pragma unroll
      for (int ni = 0; ni < 4; ++ni) {
#pragma unroll
        for (int r = 0; r < 4; ++r) {
          float p = __expf(vals[ni][r] - mx);  // masked -> exact 0
          vals[ni][r] = p;
          sum += p;
        }
      }
      sum += __shfl_xor(sum, 16);
      sum += __shfl_xor(sum, 32);
      float inv = 1.0f / sum;

      // pack normalized P^T: pk4[ni] = 4 bf16 {t = ni*16 + g*4 + r}
      u64 pk4[4];
#pragma unroll
      for (int ni = 0; ni < 4; ++ni) {
        union { __hip_bfloat16 h[4]; u64 u; } pk;
#pragma unroll
        for (int r = 0; r < 4; ++r) pk.h[r] = __float2bfloat16(vals[ni][r] * inv);
        pk4[ni] = pk.u;
      }

      // regroup to PV B-frags (row m=q16, k=t): verified 6-shfl network (R17)
      bf16x8 bp[2];
#pragma unroll
      for (int ks = 0; ks < 2; ++ks) {
        u64 A  = pk4[2 * ks];
        u64 A3 = pk4[2 * ks + 1];
        u64 B16 = __shfl_xor(A, 16);
        u64 B32 = __shfl_xor(A, 32);
        u64 B48 = __shfl_xor(A, 48);
        u64 C16 = __shfl_xor(A3, 16);
        u64 C32 = __shfl_xor(A3, 32);
        u64 C48 = __shfl_xor(A3, 48);
        u64 lo = (g == 0) ? A : (g == 1) ? B48 : (g == 2) ? C32 : C16;
        u64 hi = (g == 0) ? B16 : (g == 1) ? B32 : (g == 2) ? C48 : A3;
        union { u64 w[2]; bf16x8 v; } cb;
        cb.w[0] = lo; cb.w[1] = hi;
        bp[ks] = cb.v;
      }

      // PV: O^T[d][m] = sum_t V^T[d][t] P[m][t]; C row d = ai*16+g*4+r, col m=q16
      floatx4 o2[2];
      o2[0] = o2[1] = zc;
      __builtin_amdgcn_s_setprio(1);
#pragma unroll
      for (int ai = 0; ai < 2; ++ai)
#pragma unroll
        for (int ks = 0; ks < 2; ++ks)
          o2[ai] = MFMA16(va[ai][ks], bp[ks], o2[ai]);
      __builtin_amdgcn_s_setprio(0);

      int m = mi * 16 + q16;
      if (m < 49) {
#pragma unroll
        for (int ai = 0; ai < 2; ++ai)
#pragma unroll
          for (int r = 0; r < 4; ++r)
            o_lds[m][head * 32 + ai * 16 + g * 4 + r] = __float2bfloat16(o2[ai][r]);
      }
    }
  }

  __syncthreads();                             // all heads' O in o_lds

  // ---- proj: wave wv -> cols [wv*96, wv*96+96), 2 passes of 48 ----
#pragma unroll 1
  for (int pass = 0; pass < 2; ++pass) {
    int n0 = wv * 96 + pass * 48;
    floatx4 pacc[4][3];
#pragma unroll
    for (int i = 0; i < 4; ++i)
#pragma unroll
      for (int j = 0; j < 3; ++j) pacc[i][j] = zc;

#pragma unroll
    for (int kk = 0; kk < 12; ++kk) {
      int k0 = kk * 32;
      bf16x8 af[4], bfr[3];
#pragma unroll
      for (int mi = 0; mi < 4; ++mi) {
        int row = mi * 16 + q16;
        row = row < 49 ? row : 48;
        af[mi] = *(const bf16x8*)&o_lds[row][k0 + g * 8];
      }
#pragma unroll
      for (int ni = 0; ni < 3; ++ni)
        bfr[ni] = *(const bf16x8*)(wp + (size_t)(n0 + ni * 16 + q16) * 384 + k0 + g * 8);
      __builtin_amdgcn_s_setprio(1);
#pragma unroll
      for (int mi = 0; mi < 4; ++mi)
#pragma unroll
        for (int ni = 0; ni < 3; ++ni)
          pacc[mi][ni] = MFMA16(af[mi], bfr[ni], pacc[mi][ni]);
      __builtin_amdgcn_s_setprio(0);
    }

#pragma unroll
    for (int mi = 0; mi < 4; ++mi) {
#pragma unroll
      for (int r = 0; r < 4; ++r) {
        int m = mi * 16 + g * 4 + r;
        if (m < 49) {
          int off = dst_off(win * 49 + m);
#pragma unroll
          for (int ni = 0; ni < 3; ++ni) {
            int n = n0 + ni * 16 + q16;
            out[off + n] = pacc[mi][ni][r] + bproj[n];
          }
        }
      }
    }
  }
}

// ---------------------------------------------------------------------------
extern "C" void kernel_launch(void* const* d_in, const int* in_sizes, int n_in,
                              void* d_out, int out_size, void* d_ws, size_t ws_size,
                              hipStream_t stream) {
  const float* x         = (const float*)d_in[0];
  const float* w_qkv     = (const float*)d_in[1];
  const float* b_qkv     = (const float*)d_in[2];
  const float* w_proj    = (const float*)d_in[3];
  const float* b_proj    = (const float*)d_in[4];
  const float* rel_table = (const float*)d_in[5];
  float* out = (float*)d_out;

  char* ws = (char*)d_ws;
  // Workspace layout (total 256,376,832 B):
  const size_t OFF_WQKV  = 0;                        //   884,736
  const size_t OFF_WPROJ = 884736;                   //   294,912
  const size_t OFF_BIAS2 = 1179648;                  //   393,216
  const size_t OFF_Q     = 1572864;                  //  77,070,336
  const size_t OFF_K     = OFF_Q + 77070336;         //  77,070,336
  const size_t OFF_VT    = OFF_K + 77070336;         // 100,663,296 (v^T, 64-pad)

  __hip_bfloat16* wqkv_bf  = (__hip_bfloat16*)(ws + OFF_WQKV);
  __hip_bfloat16* wproj_bf = (__hip_bfloat16*)(ws + OFF_WPROJ);
  __hip_bfloat16* bias2    = (__hip_bfloat16*)(ws + OFF_BIAS2);
  __hip_bfloat16* qb       = (__hip_bfloat16*)(ws + OFF_Q);
  __hip_bfloat16* kb       = (__hip_bfloat16*)(ws + OFF_K);
  __hip_bfloat16* vt       = (__hip_bfloat16*)(ws + OFF_VT);
  // xw lives in d_out: dead scratch until attnproj fully overwrites out.
  __hip_bfloat16* xw       = (__hip_bfloat16*)d_out;

  // No vt memset: pad cols t=49..63 only ever multiply exactly-zero P, and
  // stale/0xAA bf16 patterns are finite, so 0*pad == 0.

  prep_kernel<<<3072, 256, 0, stream>>>(w_qkv, w_proj, rel_table, wqkv_bf, wproj_bf, bias2);
  xconv_kernel<<<18816, 256, 0, stream>>>(x, xw);
  qkv_kernel<<<7056, 256, 0, stream>>>(xw, wqkv_bf, b_qkv, qb, kb, vt);
  attnproj_kernel<<<2048, 256, 0, stream>>>(qb, kb, vt, bias2, wproj_bf, b_proj, out);
}

// Round 21
// 378.977 us; speedup vs baseline: 2.5832x; 1.3107x over previous
//
#include <hip/hip_runtime.h>
#include <hip/hip_bf16.h>

// ---------------------------------------------------------------------------
// Swin window attention, MI355X gfx950 — split pipeline (R18 + head ILP).
// prep (bf16 weights + pad-premasked frag bias) ->
//   xconv (roll+window gather, fp32->bf16, xw lives in d_out) ->
//   qkv GEMM (R18/staged: BK=64, A+B global_load_lds dbuf 64 KB, plain
//     barriers + next-tile prefetch; R20's B-direct variant was 288 us vs
//     169 — B-frag loads at 768B stride thrash L1; reverted) ->
//   attnproj (R18 + hh-loop FULLY UNROLLED: 3 heads = 3 independent chains
//     per wave; VGPR was 64 of 128 cap -> headroom for 3x live state).
// ---------------------------------------------------------------------------

typedef __bf16 bf16x8 __attribute__((ext_vector_type(8)));
typedef float  floatx4 __attribute__((ext_vector_type(4)));
typedef short  short8  __attribute__((ext_vector_type(8)));
typedef unsigned long long u64;

#define MFMA16(a, b, c) __builtin_amdgcn_mfma_f32_16x16x32_bf16((a), (b), (c), 0, 0, 0)

static __device__ __forceinline__ void gload_lds16(const void* g, void* l) {
  __builtin_amdgcn_global_load_lds(
      (const __attribute__((address_space(1))) void*)g,
      (__attribute__((address_space(3))) void*)l, 16, 0, 0);
}

static __device__ __forceinline__ int src_off(int gm) {
  int win = gm / 49, t = gm - win * 49;
  int b = win >> 6, rr = win & 63;
  int wi = rr >> 3, wj = rr & 7;
  int ty = t / 7, tx = t - ty * 7;
  int y = wi * 7 + ty + 4; if (y >= 56) y -= 56;
  int x = wj * 7 + tx + 4; if (x >= 56) x -= 56;
  return ((b * 56 + y) * 56 + x) * 384;
}

static __device__ __forceinline__ int dst_off(int gm) {
  int win = gm / 49, t = gm - win * 49;
  int b = win >> 6, rr = win & 63;
  int wi = rr >> 3, wj = rr & 7;
  int ty = t / 7, tx = t - ty * 7;
  int y = wi * 7 + ty + 3; if (y >= 56) y -= 56;
  int x = wj * 7 + tx + 3; if (x >= 56) x -= 56;
  return ((b * 56 + y) * 56 + x) * 384;
}

static __device__ __forceinline__ float bf_lo(unsigned u) {
  union { unsigned v; float f; } c; c.v = u << 16; return c.f;
}
static __device__ __forceinline__ float bf_hi(unsigned u) {
  union { unsigned v; float f; } c; c.v = u & 0xFFFF0000u; return c.f;
}

// ---------------------------------------------------------------------------
// prep: bf16 weight copies + bias2 in the TRANSPOSED (S^T) fragment layout,
// PRE-MASKED with the pad mask (m>=49 || n>=49 -> -1e30).
__global__ __launch_bounds__(256) void prep_kernel(
    const float* __restrict__ w_qkv, const float* __restrict__ w_proj,
    const float* __restrict__ rel_table,
    __hip_bfloat16* __restrict__ wqkv_bf, __hip_bfloat16* __restrict__ wproj_bf,
    __hip_bfloat16* __restrict__ bias2) {
  const int N1 = 3 * 384 * 384;   // 442368
  const int N2 = 384 * 384;       // 147456
  const int N3 = 12 * 4 * 4 * 64 * 4;  // 196608
  int i = blockIdx.x * 256 + threadIdx.x;  // grid 3072*256 = N1+N2+N3
  if (i < N1) wqkv_bf[i] = __float2bfloat16(w_qkv[i]);
  int j = i - N1;
  if (j >= 0 && j < N2) wproj_bf[j] = __float2bfloat16(w_proj[j]);
  int k = i - N1 - N2;
  if (k >= 0 && k < N3) {
    int r = k & 3;
    int lp = (k >> 2) & 63;
    int ni = (k >> 8) & 3;
    int mi = (k >> 10) & 3;
    int head = k >> 12;
    int m = mi * 16 + (lp & 15);
    int n = ni * 16 + (lp >> 4) * 4 + r;
    float val = -1e30f;
    if (m < 49 && n < 49) {
      int dy = m / 7 - n / 7 + 6;
      int dx = m % 7 - n % 7 + 6;
      val = rel_table[(dy * 13 + dx) * 12 + head];
    }
    bias2[k] = __float2bfloat16(val);
  }
}

// ---------------------------------------------------------------------------
__global__ __launch_bounds__(256) void xconv_kernel(
    const float* __restrict__ x, __hip_bfloat16* __restrict__ xw) {
  int gid = blockIdx.x * 256 + threadIdx.x;   // 4,816,896 total
  int row = gid / 48;
  int c = (gid - row * 48) * 8;
  int so = src_off(row) + c;
  floatx4 a = *(const floatx4*)(x + so);
  floatx4 b = *(const floatx4*)(x + so + 4);
  union { __hip_bfloat16 h[8]; short8 s; } u;
#pragma unroll
  for (int i = 0; i < 4; ++i) {
    u.h[i]     = __float2bfloat16(a[i]);
    u.h[4 + i] = __float2bfloat16(b[i]);
  }
  *(short8*)(xw + (size_t)row * 384 + c) = u.s;
}

// ---------------------------------------------------------------------------
// QKV GEMM (R18 staged): 128x128 tile, BK=64, A+B gload_lds dbuf (64 KB),
// plain __syncthreads + next-tile prefetch.
__global__ __launch_bounds__(256) void qkv_kernel(
    const __hip_bfloat16* __restrict__ xw, const __hip_bfloat16* __restrict__ wq,
    const float* __restrict__ bqkv,
    __hip_bfloat16* __restrict__ qb, __hip_bfloat16* __restrict__ kb,
    __hip_bfloat16* __restrict__ vt) {
  __shared__ __hip_bfloat16 lds[2 * 16384];   // 64 KB: 2 x [A 16KB | B 16KB]
  int blk = blockIdx.x;                       // 7056 = 8 * 882
  int b2 = (blk & 7) * 882 + (blk >> 3);      // XCD-chunked swizzle (bijective)
  int mt = b2 / 9, nt = b2 - mt * 9;
  int tid = threadIdx.x;
  int l = tid & 63, wv = tid >> 6;
  int wm = wv >> 1, wn = wv & 1;
  int g = l >> 4, q16 = l & 15;

  const bool swapped = (nt >= 6);             // v-blocks: C^T fragment
  const int aro = (swapped ? wn : wm) * 64;
  const int bro = (swapped ? wm : wn) * 64;

  int sr = tid >> 3;                          // 0..31
  int sc = tid & 7;
  int scs = sc ^ (sr & 7);                    // (c*32+sr)&7 == sr&7

  const __hip_bfloat16* abase = xw + (size_t)(mt * 128) * 384;
  const __hip_bfloat16* bbase = wq + (size_t)(nt * 128) * 384;

  floatx4 acc[4][4];
#pragma unroll
  for (int i = 0; i < 4; ++i)
#pragma unroll
    for (int j = 0; j < 4; ++j)
#pragma unroll
      for (int r = 0; r < 4; ++r) acc[i][j][r] = 0.f;

  auto stage = [&](int buf, int kt) {
    int k0 = kt * 64;
    __hip_bfloat16* la = lds + buf * 16384;
#pragma unroll
    for (int c = 0; c < 4; ++c) {
      int r = c * 32 + sr;
      gload_lds16(abase + (size_t)r * 384 + k0 + scs * 8, la + c * 2048 + tid * 8);
      gload_lds16(bbase + (size_t)r * 384 + k0 + scs * 8, la + 8192 + c * 2048 + tid * 8);
    }
  };

  auto compute = [&](int buf) {
    const __hip_bfloat16* la = lds + buf * 16384;
    const __hip_bfloat16* lb = la + 8192;
#pragma unroll
    for (int kk = 0; kk < 2; ++kk) {
      bf16x8 af[4], bf[4];
#pragma unroll
      for (int i = 0; i < 4; ++i) {
        int r = aro + i * 16 + q16;
        int cp = (kk * 4 + g) ^ (r & 7);      // inverse swizzle on read
        af[i] = *(const bf16x8*)(la + r * 64 + cp * 8);
      }
#pragma unroll
      for (int i = 0; i < 4; ++i) {
        int r = bro + i * 16 + q16;
        int cp = (kk * 4 + g) ^ (r & 7);
        bf[i] = *(const bf16x8*)(lb + r * 64 + cp * 8);
      }
      __builtin_amdgcn_s_setprio(1);
      if (!swapped) {
#pragma unroll
        for (int i = 0; i < 4; ++i)
#pragma unroll
          for (int j = 0; j < 4; ++j)
            acc[i][j] = MFMA16(af[i], bf[j], acc[i][j]);
      } else {
#pragma unroll
        for (int i = 0; i < 4; ++i)
#pragma unroll
          for (int j = 0; j < 4; ++j)
            acc[i][j] = MFMA16(bf[i], af[j], acc[i][j]);
      }
      __builtin_amdgcn_s_setprio(0);
    }
  };

  stage(0, 0);
  __syncthreads();                            // tile0 landed (vmcnt drain)
#pragma unroll
  for (int t = 0; t < 6; ++t) {
    if (t < 5) stage((t + 1) & 1, t + 1);     // prefetch overlaps compute(t)
    compute(t & 1);
    __syncthreads();                          // next tile landed / buf reusable
  }

  if (!swapped) {
    const bool isq = (nt < 3);
    __hip_bfloat16* ob2 = isq ? qb : kb;
#pragma unroll
    for (int ni = 0; ni < 4; ++ni) {
      int n = nt * 128 + wn * 64 + ni * 16 + q16;
      float bn = bqkv[n];
      int nn = isq ? n : (n - 384);
#pragma unroll
      for (int mi = 0; mi < 4; ++mi) {
#pragma unroll
        for (int r = 0; r < 4; ++r) {
          int gm = mt * 128 + wm * 64 + mi * 16 + g * 4 + r;
          float v = acc[mi][ni][r] + bn;
          if (isq) v *= 0.17677669529663687f;  // 1/sqrt(32) folded into q
          ob2[gm * 384 + nn] = __float2bfloat16(v);
        }
      }
    }
  } else {
    int win4[4], t4[4];
#pragma unroll
    for (int bj = 0; bj < 4; ++bj) {
      int gm = mt * 128 + wn * 64 + bj * 16 + q16;
      int w = gm / 49;
      win4[bj] = w;
      t4[bj] = gm - w * 49;
    }
#pragma unroll
    for (int ai = 0; ai < 4; ++ai) {
#pragma unroll
      for (int r = 0; r < 4; ++r) {
        int n = nt * 128 + wm * 64 + ai * 16 + g * 4 + r;
        float bn = bqkv[n];
        int nnv = n - 768;                    // head*32 + d
#pragma unroll
        for (int bj = 0; bj < 4; ++bj) {
          vt[((size_t)win4[bj] * 384 + nnv) * 64 + t4[bj]] =
              __float2bfloat16(acc[ai][bj][r] + bn);
        }
      }
    }
  }
}

// ---------------------------------------------------------------------------
// attnproj: 256 threads, 4 waves x 3 heads (hh FULLY UNROLLED for cross-head
// ILP); swapped QK^T; in-register PV via 6-shfl regroup. LDS = o_lds only
// (38,416 B) -> 4 blocks/CU.
__global__ __launch_bounds__(256, 4) void attnproj_kernel(
    const __hip_bfloat16* __restrict__ qb, const __hip_bfloat16* __restrict__ kb,
    const __hip_bfloat16* __restrict__ vt, const __hip_bfloat16* __restrict__ bias2,
    const __hip_bfloat16* __restrict__ wp, const float* __restrict__ bproj,
    float* __restrict__ out) {
  __shared__ __hip_bfloat16 o_lds[49][392];    // 38,416 B (the only LDS)
  int blk = blockIdx.x;                        // 2048 = 8 * 256
  int win = (blk & 7) * 256 + (blk >> 3);      // XCD-chunked swizzle
  int tid = threadIdx.x;
  int wv = tid >> 6, l = tid & 63;
  int g = l >> 4, q16 = l & 15;
  int wr = win & 63;
  const bool lastrow = ((wr >> 3) == 7);
  const bool lastcol = ((wr & 7) == 7);

  // shift-mask badbits only for boundary windows (pad mask is in bias2).
  unsigned long long badbits = 0ull;
  if (lastrow || lastcol) {
#pragma unroll
    for (int mi = 0; mi < 4; ++mi) {
      int m = mi * 16 + q16;
      int m7 = m % 7;
      bool m28 = (m >= 28), m74 = (m7 >= 4);
#pragma unroll
      for (int ni = 0; ni < 4; ++ni) {
#pragma unroll
        for (int r = 0; r < 4; ++r) {
          int n = ni * 16 + g * 4 + r;
          bool bad = (lastrow && (m28 != (n >= 28))) ||
                     (lastcol && (m74 != ((n % 7) >= 4)));
          if (bad) badbits |= (1ull << (mi * 16 + ni * 4 + r));
        }
      }
    }
  }

  floatx4 zc;
  zc[0] = zc[1] = zc[2] = zc[3] = 0.f;

#pragma unroll
  for (int hh = 0; hh < 3; ++hh) {
    int head = wv * 3 + hh;
    const __hip_bfloat16* qp = qb + (size_t)(win * 49) * 384 + head * 32 + g * 8;
    const __hip_bfloat16* kp = kb + (size_t)(win * 49) * 384 + head * 32 + g * 8;

    bf16x8 bk[4];
#pragma unroll
    for (int ni = 0; ni < 4; ++ni) {
      int row = ni * 16 + q16;
      row = row < 49 ? row : 48;               // pad rows masked via bias
      bk[ni] = *(const bf16x8*)(kp + row * 384);
    }
    // V^T A-frags: A[d][k=t], row d = ai*16+q16, k = ks*32+g*8 (vt: [d][t=64])
    const __hip_bfloat16* vp = vt + ((size_t)win * 384 + head * 32) * 64;
    bf16x8 va[2][2];
#pragma unroll
    for (int ai = 0; ai < 2; ++ai)
#pragma unroll
      for (int ks = 0; ks < 2; ++ks)
        va[ai][ks] = *(const bf16x8*)(vp + (ai * 16 + q16) * 64 + ks * 32 + g * 8);

    const __hip_bfloat16* b2 = bias2 + (size_t)head * 4096;

#pragma unroll
    for (int mi = 0; mi < 4; ++mi) {
      int arow = mi * 16 + q16;
      arow = arow < 49 ? arow : 48;
      bf16x8 aqm = *(const bf16x8*)(qp + arow * 384);

      floatx4 stm[4];                          // S^T[ni][this mi]
      __builtin_amdgcn_s_setprio(1);
#pragma unroll
      for (int ni = 0; ni < 4; ++ni)
        stm[ni] = MFMA16(bk[ni], aqm, zc);
      __builtin_amdgcn_s_setprio(0);

      uint2 braw[4];
#pragma unroll
      for (int ni = 0; ni < 4; ++ni)
        braw[ni] = *(const uint2*)(b2 + ((mi * 4 + ni) * 64 + l) * 4);

      float vals[4][4];
      float mx = -1e30f;
#pragma unroll
      for (int ni = 0; ni < 4; ++ni) {
#pragma unroll
        for (int r = 0; r < 4; ++r) {
          float bb = (r == 0) ? bf_lo(braw[ni].x) : (r == 1) ? bf_hi(braw[ni].x)
                     : (r == 2) ? bf_lo(braw[ni].y) : bf_hi(braw[ni].y);
          float v = stm[ni][r] + bb;           // pad entries: bb = -1e30
          if ((badbits >> (mi * 16 + ni * 4 + r)) & 1) v = -1e30f;
          vals[ni][r] = v;
          mx = fmaxf(mx, v);
        }
      }
      mx = fmaxf(mx, __shfl_xor(mx, 16));
      mx = fmaxf(mx, __shfl_xor(mx, 32));
      float sum = 0.f;
#pragma unroll
      for (int ni = 0; ni < 4; ++ni) {
#pragma unroll
        for (int r = 0; r < 4; ++r) {
          float p = __expf(vals[ni][r] - mx);  // masked -> exact 0
          vals[ni][r] = p;
          sum += p;
        }
      }
      sum += __shfl_xor(sum, 16);
      sum += __shfl_xor(sum, 32);
      float inv = 1.0f / sum;

      // pack normalized P^T: pk4[ni] = 4 bf16 {t = ni*16 + g*4 + r}
      u64 pk4[4];
#pragma unroll
      for (int ni = 0; ni < 4; ++ni) {
        union { __hip_bfloat16 h[4]; u64 u; } pk;
#pragma unroll
        for (int r = 0; r < 4; ++r) pk.h[r] = __float2bfloat16(vals[ni][r] * inv);
        pk4[ni] = pk.u;
      }

      // regroup to PV B-frags (row m=q16, k=t): verified 6-shfl network (R17)
      bf16x8 bp[2];
#pragma unroll
      for (int ks = 0; ks < 2; ++ks) {
        u64 A  = pk4[2 * ks];
        u64 A3 = pk4[2 * ks + 1];
        u64 B16 = __shfl_xor(A, 16);
        u64 B32 = __shfl_xor(A, 32);
        u64 B48 = __shfl_xor(A, 48);
        u64 C16 = __shfl_xor(A3, 16);
        u64 C32 = __shfl_xor(A3, 32);
        u64 C48 = __shfl_xor(A3, 48);
        u64 lo = (g == 0) ? A : (g == 1) ? B48 : (g == 2) ? C32 : C16;
        u64 hi = (g == 0) ? B16 : (g == 1) ? B32 : (g == 2) ? C48 : A3;
        union { u64 w[2]; bf16x8 v; } cb;
        cb.w[0] = lo; cb.w[1] = hi;
        bp[ks] = cb.v;
      }

      // PV: O^T[d][m] = sum_t V^T[d][t] P[m][t]; C row d = ai*16+g*4+r, col m=q16
      floatx4 o2[2];
      o2[0] = o2[1] = zc;
      __builtin_amdgcn_s_setprio(1);
#pragma unroll
      for (int ai = 0; ai < 2; ++ai)
#pragma unroll
        for (int ks = 0; ks < 2; ++ks)
          o2[ai] = MFMA16(va[ai][ks], bp[ks], o2[ai]);
      __builtin_amdgcn_s_setprio(0);

      int m = mi * 16 + q16;
      if (m < 49) {
#pragma unroll
        for (int ai = 0; ai < 2; ++ai)
#pragma unroll
          for (int r = 0; r < 4; ++r)
            o_lds[m][head * 32 + ai * 16 + g * 4 + r] = __float2bfloat16(o2[ai][r]);
      }
    }
  }

  __syncthreads();                             // all heads' O in o_lds

  // ---- proj: wave wv -> cols [wv*96, wv*96+96), 2 passes of 48 ----
#pragma unroll 1
  for (int pass = 0; pass < 2; ++pass) {
    int n0 = wv * 96 + pass * 48;
    floatx4 pacc[4][3];
#pragma unroll
    for (int i = 0; i < 4; ++i)
#pragma unroll
      for (int j = 0; j < 3; ++j) pacc[i][j] = zc;

#pragma unroll
    for (int kk = 0; kk < 12; ++kk) {
      int k0 = kk * 32;
      bf16x8 af[4], bfr[3];
#pragma unroll
      for (int mi = 0; mi < 4; ++mi) {
        int row = mi * 16 + q16;
        row = row < 49 ? row : 48;
        af[mi] = *(const bf16x8*)&o_lds[row][k0 + g * 8];
      }
#pragma unroll
      for (int ni = 0; ni < 3; ++ni)
        bfr[ni] = *(const bf16x8*)(wp + (size_t)(n0 + ni * 16 + q16) * 384 + k0 + g * 8);
      __builtin_amdgcn_s_setprio(1);
#pragma unroll
      for (int mi = 0; mi < 4; ++mi)
#pragma unroll
        for (int ni = 0; ni < 3; ++ni)
          pacc[mi][ni] = MFMA16(af[mi], bfr[ni], pacc[mi][ni]);
      __builtin_amdgcn_s_setprio(0);
    }

#pragma unroll
    for (int mi = 0; mi < 4; ++mi) {
#pragma unroll
      for (int r = 0; r < 4; ++r) {
        int m = mi * 16 + g * 4 + r;
        if (m < 49) {
          int off = dst_off(win * 49 + m);
#pragma unroll
          for (int ni = 0; ni < 3; ++ni) {
            int n = n0 + ni * 16 + q16;
            out[off + n] = pacc[mi][ni][r] + bproj[n];
          }
        }
      }
    }
  }
}

// ---------------------------------------------------------------------------
extern "C" void kernel_launch(void* const* d_in, const int* in_sizes, int n_in,
                              void* d_out, int out_size, void* d_ws, size_t ws_size,
                              hipStream_t stream) {
  const float* x         = (const float*)d_in[0];
  const float* w_qkv     = (const float*)d_in[1];
  const float* b_qkv     = (const float*)d_in[2];
  const float* w_proj    = (const float*)d_in[3];
  const float* b_proj    = (const float*)d_in[4];
  const float* rel_table = (const float*)d_in[5];
  float* out = (float*)d_out;

  char* ws = (char*)d_ws;
  // Workspace layout (total 256,376,832 B):
  const size_t OFF_WQKV  = 0;                        //   884,736
  const size_t OFF_WPROJ = 884736;                   //   294,912
  const size_t OFF_BIAS2 = 1179648;                  //   393,216
  const size_t OFF_Q     = 1572864;                  //  77,070,336
  const size_t OFF_K     = OFF_Q + 77070336;         //  77,070,336
  const size_t OFF_VT    = OFF_K + 77070336;         // 100,663,296 (v^T, 64-pad)

  __hip_bfloat16* wqkv_bf  = (__hip_bfloat16*)(ws + OFF_WQKV);
  __hip_bfloat16* wproj_bf = (__hip_bfloat16*)(ws + OFF_WPROJ);
  __hip_bfloat16* bias2    = (__hip_bfloat16*)(ws + OFF_BIAS2);
  __hip_bfloat16* qb       = (__hip_bfloat16*)(ws + OFF_Q);
  __hip_bfloat16* kb       = (__hip_bfloat16*)(ws + OFF_K);
  __hip_bfloat16* vt       = (__hip_bfloat16*)(ws + OFF_VT);
  // xw lives in d_out: dead scratch until attnproj fully overwrites out.
  __hip_bfloat16* xw       = (__hip_bfloat16*)d_out;

  // No vt memset: pad cols t=49..63 only ever multiply exactly-zero P, and
  // stale/0xAA bf16 patterns are finite, so 0*pad == 0.

  prep_kernel<<<3072, 256, 0, stream>>>(w_qkv, w_proj, rel_table, wqkv_bf, wproj_bf, bias2);
  xconv_kernel<<<18816, 256, 0, stream>>>(x, xw);
  qkv_kernel<<<7056, 256, 0, stream>>>(xw, wqkv_bf, b_qkv, qb, kb, vt);
  attnproj_kernel<<<2048, 256, 0, stream>>>(qb, kb, vt, bias2, wproj_bf, b_proj, out);
}